// Round 1
// baseline (756.681 us; speedup 1.0000x reference)
//
#include <hip/hip_runtime.h>
#include <math.h>

// LaplacianLoss: out[b] = vertex_weight * ||L @ x[b]||_F * NV
// L: 10000x10000 fp32 (400 MB, streamed once, HBM-bound ~63.5us floor)
// x: 8x10000x3 fp32 (960 KB, L2-resident, staged per-tile in LDS)
//
// Decomposition: C[i, n=(b*3+k)] = sum_j L[i,j] * X[j,n]  (skinny GEMM, N=24)
// 500 blocks x 256 thr; wave owns 5 rows; lanes split j (coalesced L dwords).
// LDS x-tile Xs[jj][28]: pad to 28 floats so lane-stride-112B ds_read_b128
// hits the uniform 8-access/bank optimum. Epilogue: LDS transpose reduction
// (sum over lanes BEFORE squaring), block atomics -> counter -> last block
// finalizes sqrt.

#define NV 10000
#define BATCH 8
#define TJ 256
#define NTILE 40            // 39 full tiles + tail of 16 columns
#define ROWS_PER_WAVE 5
#define ROWS_PER_BLOCK 20   // 4 waves * 5 rows
#define GRID_MAIN 500       // 500 * 20 = 10000 rows exactly

__global__ __launch_bounds__(256) void lap_main(
    const float* __restrict__ x, const float* __restrict__ L,
    const float* __restrict__ wv, float* __restrict__ out,
    float* __restrict__ Sg, unsigned* __restrict__ ctr) {
  // smem union: Xs = [256][28] = 7168 floats ; Ps = [64 lanes][124] = 7936 floats
  __shared__ float smem[7936];
  __shared__ float sS[8];

  const int tid  = threadIdx.x;
  const int lane = tid & 63;
  const int wave = tid >> 6;
  const long r0  = (long)blockIdx.x * ROWS_PER_BLOCK + (long)wave * ROWS_PER_WAVE;

  float4 acc[ROWS_PER_WAVE][6];
#pragma unroll
  for (int r = 0; r < ROWS_PER_WAVE; ++r)
#pragma unroll
    for (int c = 0; c < 6; ++c) acc[r][c] = make_float4(0.f, 0.f, 0.f, 0.f);
  if (tid < 8) sS[tid] = 0.f;

  // Staging scatter offsets: within-tile flat element e = 4*tid + i  ->
  // jj = e/3, k = e%3, LDS offset jj*28 + b*3 + k. Tile/batch independent.
  int soff[4];
#pragma unroll
  for (int i = 0; i < 4; ++i) {
    int e = 4 * tid + i;
    soff[i] = (e / 3) * 28 + (e % 3);
  }

  const float4* __restrict__ xg = (const float4*)x;       // x is fp32, 16B aligned
  const float* __restrict__ Lp  = L + r0 * (long)NV + lane;

  for (int t = 0; t < NTILE; ++t) {
    const int jcount = (t == NTILE - 1) ? (NV - t * TJ) : TJ;  // 256 or 16
    __syncthreads();  // previous tile's compute done before overwriting Xs

    // ---- stage x tile: global float4 loads, scalar scatter into Xs[jj][28] ----
    const int nf4 = (jcount * 3) >> 2;  // 192 (full) or 12 (tail) float4s per batch
    if (tid < nf4) {
#pragma unroll
      for (int b = 0; b < BATCH; ++b) {
        float4 v = xg[b * 7500 + t * 192 + tid];
        smem[soff[0] + b * 3] = v.x;
        smem[soff[1] + b * 3] = v.y;
        smem[soff[2] + b * 3] = v.z;
        smem[soff[3] + b * 3] = v.w;
      }
    }
    __syncthreads();

    // ---- compute: each lane: 1 column per q-step, 5 rows, 24 n ----
    if (t < NTILE - 1) {
#pragma unroll
      for (int q = 0; q < 4; ++q) {
        const int jj = q * 64 + lane;
        const float* xs = &smem[jj * 28];
        float4 xv[6];
#pragma unroll
        for (int c = 0; c < 6; ++c) xv[c] = *(const float4*)(xs + 4 * c);
        float lv[ROWS_PER_WAVE];
#pragma unroll
        for (int r = 0; r < ROWS_PER_WAVE; ++r)
          lv[r] = __builtin_nontemporal_load(Lp + (long)r * NV + t * TJ + q * 64);
#pragma unroll
        for (int r = 0; r < ROWS_PER_WAVE; ++r) {
          const float s = lv[r];
#pragma unroll
          for (int c = 0; c < 6; ++c) {
            acc[r][c].x += s * xv[c].x;
            acc[r][c].y += s * xv[c].y;
            acc[r][c].z += s * xv[c].z;
            acc[r][c].w += s * xv[c].w;
          }
        }
      }
    } else {
      // tail tile: 16 columns, lanes 0..15 active, q = 0 only
      if (lane < jcount) {
        const float* xs = &smem[lane * 28];
        float4 xv[6];
#pragma unroll
        for (int c = 0; c < 6; ++c) xv[c] = *(const float4*)(xs + 4 * c);
#pragma unroll
        for (int r = 0; r < ROWS_PER_WAVE; ++r) {
          const float s = __builtin_nontemporal_load(Lp + (long)r * NV + t * TJ);
#pragma unroll
          for (int c = 0; c < 6; ++c) {
            acc[r][c].x += s * xv[c].x;
            acc[r][c].y += s * xv[c].y;
            acc[r][c].z += s * xv[c].z;
            acc[r][c].w += s * xv[c].w;
          }
        }
      }
    }
  }

  // ---- epilogue: cross-lane sum per (row, n), then square, then reduce ----
  // 4 rounds (one per wave): wave w dumps its 64x120 partials into Ps[lane][124]
  // (stride 124 floats: float4 writes at lane-stride 496B = uniform banks),
  // then threads 0..119 sum over the 64 lanes and accumulate the square.
  float local_sq = 0.f;
  const int bIdx = (tid % 24) / 3;   // batch of this thread's (row,n) combo
  for (int w = 0; w < 4; ++w) {
    __syncthreads();
    if (wave == w) {
#pragma unroll
      for (int r = 0; r < ROWS_PER_WAVE; ++r)
#pragma unroll
        for (int c = 0; c < 6; ++c)
          *(float4*)&smem[lane * 124 + r * 24 + c * 4] = acc[r][c];
    }
    __syncthreads();
    if (tid < 120) {
      float s = 0.f;
#pragma unroll
      for (int l = 0; l < 64; ++l) s += smem[l * 124 + tid];
      local_sq += s * s;   // this thread's (row,n) is complete: square now
    }
  }
  if (tid < 120) atomicAdd(&sS[bIdx], local_sq);
  __syncthreads();
  if (tid < 8) atomicAdd(&Sg[tid], sS[tid]);
  __syncthreads();  // drains the global atomics (vmcnt(0)) before the flag

  if (tid == 0) {
    __threadfence();
    unsigned old = atomicAdd(ctr, 1u);
    if (old == (unsigned)(gridDim.x - 1)) {
      __threadfence();
      const float w = wv[0];
#pragma unroll
      for (int b = 0; b < BATCH; ++b) {
        float s = atomicAdd(&Sg[b], 0.f);  // coherent L2 read
        out[b] = w * sqrtf(s) * (float)NV;
      }
    }
  }
}

extern "C" void kernel_launch(void* const* d_in, const int* in_sizes, int n_in,
                              void* d_out, int out_size, void* d_ws, size_t ws_size,
                              hipStream_t stream) {
  const float* x  = (const float*)d_in[0];   // (8, 10000, 3) fp32
  const float* L  = (const float*)d_in[1];   // (10000, 10000) fp32
  const float* wv = (const float*)d_in[2];   // (1,) fp32
  float* out = (float*)d_out;                // (8,) fp32

  float* Sg = (float*)d_ws;                        // 8 fp32 accumulators
  unsigned* ctr = (unsigned*)((char*)d_ws + 32);   // completion counter

  hipMemsetAsync(d_ws, 0, 64, stream);
  lap_main<<<GRID_MAIN, 256, 0, stream>>>(x, L, wv, out, Sg, ctr);
}

// Round 2
// 629.651 us; speedup vs baseline: 1.2017x; 1.2017x over previous
//
#include <hip/hip_runtime.h>
#include <math.h>

// LaplacianLoss: out[b] = vertex_weight * ||L @ x[b]||_F * NV
// L: 10000x10000 fp32 (400 MB streamed; ~205 MB from HBM thanks to L3).
// Round-2 structure: latency-tolerant streaming skinny GEMM.
//  - grid = 625 row-groups x 4 j-groups = 2500 blocks (~10/CU queued)
//  - wave owns 4 rows; lane owns 4 consecutive columns -> float4 L loads
//  - x tile staged in LDS in natural [b][j][k] layout (float4 copy, no
//    scatter, conflict-free), compute reads 3x ds_read_b128 per batch at
//    48B lane stride (conflict-free: gcd(12,32)=4 covers all banks per 8 lanes)
//  - partial sums over j-ranges atomicAdd'ed into C[10000][24] in d_ws
//    (sum over j BEFORE squaring), then lap_reduce squares + reduces + sqrt.

#define NVERT 10000
#define TJ 256
#define NTILES 40     // 39 full tiles + 16-column tail
#define TPG 10        // tiles per j-group
#define JG 4
#define RPW 4         // rows per wave
#define RPB 16        // rows per block (4 waves)
#define NROWG 625
#define GRID1 (NROWG * JG)
#define GRID2 40

__global__ __launch_bounds__(256, 3) void lap_main(
    const float* __restrict__ x, const float* __restrict__ L,
    float* __restrict__ C) {
  // staging view: [b][192 float4] = 6144 floats; epilogue view: [64][100] = 6400
  __shared__ __align__(16) float smem[6400];

  const int tid  = threadIdx.x;
  const int lane = tid & 63;
  const int wave = tid >> 6;
  const int rg   = blockIdx.x >> 2;   // row-group
  const int jg   = blockIdx.x & 3;    // j-group
  const int row0 = rg * RPB + wave * RPW;

  __align__(16) float acc[RPW][24];
#pragma unroll
  for (int r = 0; r < RPW; ++r)
#pragma unroll
    for (int n = 0; n < 24; ++n) acc[r][n] = 0.f;

  const float4* __restrict__ xg = (const float4*)x;  // [b][2500 float4]

  for (int tt = 0; tt < TPG; ++tt) {
    const int t = jg * TPG + tt;
    const int jcount = (t == NTILES - 1) ? (NVERT - t * TJ) : TJ;  // 256 or 16
    __syncthreads();  // previous tile's LDS reads done

    // ---- stage x tile: straight float4 copy, layout [b][j][k] ----
    const int nf4 = (jcount * 3) >> 2;  // 192 or 12 float4 per batch
    if (tid < nf4) {
#pragma unroll
      for (int b = 0; b < 8; ++b)
        ((float4*)smem)[b * 192 + tid] = xg[b * 7500 + t * 192 + tid];
    }
    __syncthreads();

    // ---- compute: lane owns columns col0..col0+3 ----
    const int col0 = t * TJ + 4 * lane;
    if (4 * lane < jcount) {
      __align__(16) float Lv[RPW][4];
#pragma unroll
      for (int r = 0; r < RPW; ++r)
        *(float4*)&Lv[r][0] =
            *(const float4*)(L + (long)(row0 + r) * NVERT + col0);

      const float* xs = smem + 12 * lane;
#pragma unroll
      for (int b = 0; b < 8; ++b) {
        __align__(16) float xv[12];
        *(float4*)&xv[0] = *(const float4*)(xs + b * 768);
        *(float4*)&xv[4] = *(const float4*)(xs + b * 768 + 4);
        *(float4*)&xv[8] = *(const float4*)(xs + b * 768 + 8);
#pragma unroll
        for (int r = 0; r < RPW; ++r)
#pragma unroll
          for (int jj = 0; jj < 4; ++jj)
#pragma unroll
            for (int k = 0; k < 3; ++k)
              acc[r][b * 3 + k] += Lv[r][jj] * xv[jj * 3 + k];
      }
    }
  }

  // ---- epilogue: cross-lane sum per (row, n), atomic into C ----
  // 4 rounds; wave w dumps 64 lanes x 96 floats at stride 100 (conflict-free:
  // 100 mod 32 = 4 -> 8 lanes cover all 32 banks), threads<96 sum 64 lanes.
  for (int w = 0; w < 4; ++w) {
    __syncthreads();
    if (wave == w) {
#pragma unroll
      for (int r = 0; r < RPW; ++r)
#pragma unroll
        for (int c = 0; c < 6; ++c)
          *(float4*)&smem[lane * 100 + r * 24 + c * 4] = *(float4*)&acc[r][c * 4];
    }
    __syncthreads();
    if (tid < 96) {
      float s = 0.f;
#pragma unroll
      for (int l = 0; l < 64; ++l) s += smem[l * 100 + tid];
      const int row = rg * RPB + w * RPW + tid / 24;
      atomicAdd(&C[row * 24 + (tid % 24)], s);
    }
  }
}

__global__ __launch_bounds__(256) void lap_reduce(
    const float* __restrict__ C, const float* __restrict__ wv,
    float* __restrict__ out, float* __restrict__ Sg, unsigned* __restrict__ ctr) {
  __shared__ float sS[8];
  const int tid = threadIdx.x;
  if (tid < 8) sS[tid] = 0.f;
  __syncthreads();

  const int row = blockIdx.x * 256 + tid;  // one row per thread (10240 >= 10000)
  float pb[8] = {0.f, 0.f, 0.f, 0.f, 0.f, 0.f, 0.f, 0.f};
  if (row < NVERT) {
    const float* rp = C + (long)row * 24;
#pragma unroll
    for (int b = 0; b < 8; ++b) {
      float s = 0.f;
#pragma unroll
      for (int k = 0; k < 3; ++k) {
        float v = rp[b * 3 + k];
        s += v * v;
      }
      pb[b] = s;
    }
  }
#pragma unroll
  for (int b = 0; b < 8; ++b) atomicAdd(&sS[b], pb[b]);
  __syncthreads();
  if (tid < 8) atomicAdd(&Sg[tid], sS[tid]);
  __syncthreads();  // drains global atomics before the flag

  if (tid == 0) {
    __threadfence();
    unsigned old = atomicAdd(ctr, 1u);
    if (old == (unsigned)(gridDim.x - 1)) {
      __threadfence();
      const float w = wv[0];
#pragma unroll
      for (int b = 0; b < 8; ++b) {
        float s = atomicAdd(&Sg[b], 0.f);  // coherent read
        out[b] = w * sqrtf(s) * (float)NVERT;
      }
    }
  }
}

extern "C" void kernel_launch(void* const* d_in, const int* in_sizes, int n_in,
                              void* d_out, int out_size, void* d_ws, size_t ws_size,
                              hipStream_t stream) {
  const float* x  = (const float*)d_in[0];   // (8, 10000, 3) fp32
  const float* L  = (const float*)d_in[1];   // (10000, 10000) fp32
  const float* wv = (const float*)d_in[2];   // (1,) fp32
  float* out = (float*)d_out;                // (8,) fp32

  float* C       = (float*)d_ws;                         // 240000 floats
  float* Sg      = (float*)((char*)d_ws + 960000);       // 8 floats
  unsigned* ctr  = (unsigned*)((char*)d_ws + 960032);    // counter

  hipMemsetAsync(d_ws, 0, 960064, stream);
  lap_main<<<GRID1, 256, 0, stream>>>(x, L, C);
  lap_reduce<<<GRID2, 256, 0, stream>>>(C, wv, out, Sg, ctr);
}